// Round 4
// baseline (2668.969 us; speedup 1.0000x reference)
//
#include <hip/hip_runtime.h>
#include <float.h>

// ---------------------------------------------------------------------------
// GEMM with f64 accumulation: C[M,N] = op(A[M,K]) @ W[K,N] + bias (f32 store).
// op = identity, or (FUSE) per-K-column BN+ReLU in f64:
//   a -> max(fma((double)a, scl[k], shf[k]), 0.0)
// Tile 128(M) x 64(N), BK=16, 256 threads, 8x4 f64 micro-tile per thread.
// LDS tiles staged as f64 (cvt once at stage time). 24 KB LDS -> 6 blocks/CU.
// ---------------------------------------------------------------------------
template<bool FUSE>
__global__ __launch_bounds__(256)
void gemm_f64(const float* __restrict__ A, const float* __restrict__ W,
              const float* __restrict__ bias,
              const double* __restrict__ scl, const double* __restrict__ shf,
              float* __restrict__ C, int M, int N, int K)
{
    __shared__ double Asd[16][128];   // [k][row] 16 KB
    __shared__ double Bsd[16][64];    // [k][col]  8 KB
    const int tid = threadIdx.x;
    const int tx = tid & 15;
    const int ty = tid >> 4;
    const int rowBase = blockIdx.y << 7;
    const int colBase = blockIdx.x << 6;

    const float* Ab = A + (size_t)rowBase * K;
    const float* Wb = W + colBase;

    double acc[8][4];
    #pragma unroll
    for (int i = 0; i < 8; ++i)
        #pragma unroll
        for (int j = 0; j < 4; ++j) acc[i][j] = 0.0;

    for (int k0 = 0; k0 < K; k0 += 16) {
        // A tile: 128 rows x 16 k  (512 float4, 2 per thread), transposed store
        #pragma unroll
        for (int l = 0; l < 2; ++l) {
            int li = (l << 8) + tid;
            int r  = li >> 2;
            int c4 = (li & 3) << 2;
            float4 v = *reinterpret_cast<const float4*>(Ab + (size_t)r * K + (k0 + c4));
            double d0 = (double)v.x, d1 = (double)v.y, d2 = (double)v.z, d3 = (double)v.w;
            if (FUSE) {
                int kk = k0 + c4;
                d0 = fmax(fma(d0, scl[kk+0], shf[kk+0]), 0.0);
                d1 = fmax(fma(d1, scl[kk+1], shf[kk+1]), 0.0);
                d2 = fmax(fma(d2, scl[kk+2], shf[kk+2]), 0.0);
                d3 = fmax(fma(d3, scl[kk+3], shf[kk+3]), 0.0);
            }
            Asd[c4+0][r] = d0; Asd[c4+1][r] = d1; Asd[c4+2][r] = d2; Asd[c4+3][r] = d3;
        }
        // B tile: 16 k x 64 cols (256 float4, 1 per thread)
        {
            int kr = tid >> 4;
            int cc = (tid & 15) << 2;
            float4 w = *reinterpret_cast<const float4*>(Wb + (size_t)(k0 + kr) * N + cc);
            Bsd[kr][cc+0] = (double)w.x; Bsd[kr][cc+1] = (double)w.y;
            Bsd[kr][cc+2] = (double)w.z; Bsd[kr][cc+3] = (double)w.w;
        }
        __syncthreads();
        #pragma unroll
        for (int k = 0; k < 16; ++k) {
            double a[8], b[4];
            #pragma unroll
            for (int i = 0; i < 8; ++i) a[i] = Asd[k][(ty << 3) + i];
            #pragma unroll
            for (int j = 0; j < 4; ++j) b[j] = Bsd[k][(tx << 2) + j];
            #pragma unroll
            for (int i = 0; i < 8; ++i)
                #pragma unroll
                for (int j = 0; j < 4; ++j)
                    acc[i][j] = fma(a[i], b[j], acc[i][j]);
        }
        __syncthreads();
    }

    double bv[4];
    #pragma unroll
    for (int j = 0; j < 4; ++j) bv[j] = (double)bias[colBase + (tx << 2) + j];
    #pragma unroll
    for (int i = 0; i < 8; ++i) {
        size_t row = (size_t)rowBase + (ty << 3) + i;
        float* cp = C + row * N + colBase + (tx << 2);
        #pragma unroll
        for (int j = 0; j < 4; ++j) cp[j] = (float)(acc[i][j] + bv[j]);
    }
}

// ---------------------------------------------------------------------------
// Column stats (f64, deterministic two-stage, no atomics).
// ---------------------------------------------------------------------------
__global__ __launch_bounds__(256)
void colstats_f64(const float* __restrict__ C, double* __restrict__ ps,
                  double* __restrict__ ps2, int N, int rowsPer)
{
    int col = blockIdx.x * 256 + threadIdx.x;
    const float* p = C + (size_t)blockIdx.y * rowsPer * N + col;
    double s = 0.0, s2 = 0.0;
    for (int r = 0; r < rowsPer; ++r) {
        double v = (double)p[(size_t)r * N];
        s += v;
        s2 = fma(v, v, s2);
    }
    ps [blockIdx.y * N + col] = s;
    ps2[blockIdx.y * N + col] = s2;
}

__global__ __launch_bounds__(256)
void bn_finalize_f64(const double* __restrict__ ps, const double* __restrict__ ps2,
                     const float* __restrict__ gamma, const float* __restrict__ beta,
                     double* __restrict__ scl, double* __restrict__ shf,
                     int N, int chunks, double invM)
{
    int col = blockIdx.x * 256 + threadIdx.x;
    if (col >= N) return;
    double s = 0.0, s2 = 0.0;
    for (int c = 0; c < chunks; ++c) { s += ps[c * N + col]; s2 += ps2[c * N + col]; }
    double mean = s * invM;
    double var  = fma(s2, invM, -mean * mean);
    double sc = (double)gamma[col] / sqrt(var + 1e-5);
    scl[col] = sc;
    shf[col] = fma(-mean, sc, (double)beta[col]);
}

// ||c_j||^2 per codebook row, f64
__global__ __launch_bounds__(256)
void cnorm_f64(const float* __restrict__ cb, double* __restrict__ cn)
{
    int j = blockIdx.x * 256 + threadIdx.x;   // 0..1023
    const float* p = cb + (size_t)j * 128;
    double s = 0.0;
    #pragma unroll 4
    for (int d = 0; d < 128; ++d) { double v = (double)p[d]; s = fma(v, v, s); }
    cn[j] = s;
}

// ---------------------------------------------------------------------------
// VQ, f64: per block 64 z-rows (BN2 applied in f64 on load, z held as f64 in
// LDS), loop 1024 codes in chunks of 128, f64 dots, running (min,idx) with
// first-occurrence tie-break, gather codebook rows into out.
// d = ||c||^2 - 2 z.c  (||z||^2 constant per row; f64 makes the drop safe).
// LDS: 64 KB Zs + 8 KB Bs + 256 B -> 2 blocks/CU.
// ---------------------------------------------------------------------------
__global__ __launch_bounds__(256)
void vq_f64(const float* __restrict__ Z, const double* __restrict__ scl,
            const double* __restrict__ shf, const float* __restrict__ cb,
            const double* __restrict__ cn, float* __restrict__ out)
{
    __shared__ double Zsd[128][64];  // [dim][row] 64 KB
    __shared__ float  Bs[16][128];   // [k][code]   8 KB
    __shared__ int    rowIdx[64];

    const int tid = threadIdx.x;
    const int tx = tid & 15, ty = tid >> 4;
    const size_t zbase = (size_t)blockIdx.x << 13;   // *64*128

    // load + BN2 (f64): flat offset f -> BN column = ((m&3)<<7)+d
    #pragma unroll
    for (int l = 0; l < 8; ++l) {
        int li = (l << 8) + tid;          // float4 index 0..2047
        int m  = li >> 5;
        int d0 = (li & 31) << 2;
        float4 v = *reinterpret_cast<const float4*>(Z + zbase + ((size_t)li << 2));
        int sb = ((m & 3) << 7) + d0;
        Zsd[d0+0][m] = fma((double)v.x, scl[sb+0], shf[sb+0]);
        Zsd[d0+1][m] = fma((double)v.y, scl[sb+1], shf[sb+1]);
        Zsd[d0+2][m] = fma((double)v.z, scl[sb+2], shf[sb+2]);
        Zsd[d0+3][m] = fma((double)v.w, scl[sb+3], shf[sb+3]);
    }

    double bestV[4]; int bestI[4];
    #pragma unroll
    for (int i = 0; i < 4; ++i) { bestV[i] = DBL_MAX; bestI[i] = 0x7fffffff; }

    for (int cc = 0; cc < 1024; cc += 128) {
        double acc[4][8];
        #pragma unroll
        for (int i = 0; i < 4; ++i)
            #pragma unroll
            for (int j = 0; j < 8; ++j) acc[i][j] = 0.0;

        for (int k0 = 0; k0 < 128; k0 += 16) {
            __syncthreads();   // prev compute done (first iter: Zsd visible)
            #pragma unroll
            for (int l = 0; l < 2; ++l) {
                int li = (l << 8) + tid;
                int code = li >> 2;
                int c4 = (li & 3) << 2;
                float4 v = *reinterpret_cast<const float4*>(
                    cb + ((size_t)(cc + code) << 7) + k0 + c4);
                Bs[c4+0][code] = v.x; Bs[c4+1][code] = v.y;
                Bs[c4+2][code] = v.z; Bs[c4+3][code] = v.w;
            }
            __syncthreads();
            #pragma unroll
            for (int k = 0; k < 16; ++k) {
                double a[4], b[8];
                #pragma unroll
                for (int i = 0; i < 4; ++i) a[i] = Zsd[k0+k][(ty << 2) + i];
                #pragma unroll
                for (int j = 0; j < 4; ++j) {
                    b[j]   = (double)Bs[k][(tx << 2) + j];
                    b[4+j] = (double)Bs[k][64 + (tx << 2) + j];
                }
                #pragma unroll
                for (int i = 0; i < 4; ++i)
                    #pragma unroll
                    for (int j = 0; j < 8; ++j)
                        acc[i][j] = fma(a[i], b[j], acc[i][j]);
            }
        }
        // scores + running argmin (codes ascend within thread -> first occurrence)
        #pragma unroll
        for (int i = 0; i < 4; ++i) {
            #pragma unroll
            for (int j = 0; j < 8; ++j) {
                int code = cc + ((j < 4) ? ((tx << 2) + j) : (64 + (tx << 2) + (j - 4)));
                double d = fma(-2.0, acc[i][j], cn[code]);
                if (d < bestV[i] || (d == bestV[i] && code < bestI[i])) {
                    bestV[i] = d; bestI[i] = code;
                }
            }
        }
    }

    // cross-tx (lane bits 0..3) min-reduce with lowest-index tie-break
    #pragma unroll
    for (int i = 0; i < 4; ++i) {
        double v = bestV[i]; int idx = bestI[i];
        #pragma unroll
        for (int m = 1; m <= 8; m <<= 1) {
            double ov = __shfl_xor(v, m, 64);
            int    oi = __shfl_xor(idx, m, 64);
            if (ov < v || (ov == v && oi < idx)) { v = ov; idx = oi; }
        }
        if (tx == 0) rowIdx[(ty << 2) + i] = idx;
    }
    __syncthreads();

    // gather codebook rows -> out (overwrites the region this block read)
    #pragma unroll
    for (int l = 0; l < 8; ++l) {
        int li = (l << 8) + tid;
        int m  = li >> 5;
        int d0 = (li & 31) << 2;
        float4 v = *reinterpret_cast<const float4*>(cb + ((size_t)rowIdx[m] << 7) + d0);
        *reinterpret_cast<float4*>(out + zbase + ((size_t)li << 2)) = v;
    }
}

// ---------------------------------------------------------------------------
extern "C" void kernel_launch(void* const* d_in, const int* in_sizes, int n_in,
                              void* d_out, int out_size, void* d_ws, size_t ws_size,
                              hipStream_t stream)
{
    const float* x      = (const float*)d_in[0];
    const float* ew1    = (const float*)d_in[1];
    const float* eb1    = (const float*)d_in[2];
    const float* eg1    = (const float*)d_in[3];
    const float* ebt1   = (const float*)d_in[4];
    const float* ew2    = (const float*)d_in[5];
    const float* eb2    = (const float*)d_in[6];
    const float* eg2    = (const float*)d_in[7];
    const float* ebt2   = (const float*)d_in[8];
    const float* cb     = (const float*)d_in[9];
    float* out = (float*)d_out;

    constexpr int M  = 32768;
    constexpr int K1 = 512;
    constexpr int N1 = 1024;   // H_enc
    constexpr int N2 = 512;    // Cout
    constexpr int CHUNKS = 64;

    // workspace carve. C1 f32 (128 MB, 8B-aligned boundary), then f64 scratch.
    float*  C1   = (float*)d_ws;                      // M*N1 floats
    double* psd  = (double*)(C1 + (size_t)M * N1);    // 64*1024
    double* ps2d = psd  + (size_t)CHUNKS * N1;        // 64*1024
    double* scl1 = ps2d + (size_t)CHUNKS * N1;        // 1024
    double* shf1 = scl1 + N1;
    double* scl2 = shf1 + N1;                         // 512
    double* shf2 = scl2 + N2;
    double* cnd  = shf2 + N2;                         // 1024
    float*  C2   = out;                               // VQ reads region into LDS before overwrite

    // 1) C1 = x @ w1 + b1  (f64 accumulate)
    gemm_f64<false><<<dim3(N1/64, M/128), 256, 0, stream>>>(
        x, ew1, eb1, nullptr, nullptr, C1, M, N1, K1);
    // 2) BN1 stats (f64)
    colstats_f64<<<dim3(N1/256, CHUNKS), 256, 0, stream>>>(C1, psd, ps2d, N1, M/CHUNKS);
    bn_finalize_f64<<<dim3(N1/256), 256, 0, stream>>>(psd, ps2d, eg1, ebt1, scl1, shf1,
                                                      N1, CHUNKS, 1.0/M);
    // 3) C2 = relu(BN1(C1)) @ w2 + b2  (BN+ReLU fused in f64)
    gemm_f64<true><<<dim3(N2/64, M/128), 256, 0, stream>>>(
        C1, ew2, eb2, scl1, shf1, C2, M, N2, N1);
    // 4) BN2 stats (f64)
    colstats_f64<<<dim3(N2/256, CHUNKS), 256, 0, stream>>>(C2, psd, ps2d, N2, M/CHUNKS);
    bn_finalize_f64<<<dim3(N2/256), 256, 0, stream>>>(psd, ps2d, eg2, ebt2, scl2, shf2,
                                                      N2, CHUNKS, 1.0/M);
    // 5) VQ (f64 distances)
    cnorm_f64<<<dim3(4), 256, 0, stream>>>(cb, cnd);
    vq_f64<<<dim3(M*4/64), 256, 0, stream>>>(C2, scl2, shf2, cb, cnd, out);
}